// Round 1
// baseline (809.126 us; speedup 1.0000x reference)
//
#include <hip/hip_runtime.h>

constexpr int N_NODES  = 100000;
constexpr int N_EDGES  = 3200000;
constexpr int N_GRAPHS = 512;
constexpr int HID      = 32;

// ---------------- Phase 1: in-degree (edges only; +1 self-loop added later) --
__global__ void deg_kernel(const int* __restrict__ col, float* __restrict__ deg) {
    int e = blockIdx.x * blockDim.x + threadIdx.x;
    if (e < N_EDGES) atomicAdd(&deg[col[e]], 1.0f);
}

// ---------------- Phase 2: dinv = rsqrt(deg + 1) (in place) ------------------
__global__ void dinv_kernel(float* __restrict__ deg_dinv) {
    int i = blockIdx.x * blockDim.x + threadIdx.x;
    if (i < N_NODES) deg_dinv[i] = rsqrtf(deg_dinv[i] + 1.0f);
}

// ---------------- Phase 3: conv1 scalar aggregation (edges only) -------------
__global__ void s_kernel(const int* __restrict__ row, const int* __restrict__ col,
                         const float* __restrict__ x, const float* __restrict__ dinv,
                         float* __restrict__ s) {
    int e = blockIdx.x * blockDim.x + threadIdx.x;
    if (e < N_EDGES) {
        int j = row[e], i = col[e];
        atomicAdd(&s[i], dinv[j] * dinv[i] * x[j]);
    }
}

// ---------------- Phase 4: per-node h2pre = relu(s_tot*W1+b1) @ W2 -----------
__global__ void h2pre_kernel(const float* __restrict__ x, const float* __restrict__ dinv,
                             const float* __restrict__ s,
                             const float* __restrict__ W1, const float* __restrict__ b1,
                             const float* __restrict__ W2,
                             float* __restrict__ h2pre) {
    __shared__ float sW1[HID], sb1[HID], sW2[HID * HID];
    int tid = threadIdx.x;
    for (int t = tid; t < HID * HID; t += blockDim.x) sW2[t] = W2[t];
    if (tid < HID) { sW1[tid] = W1[tid]; sb1[tid] = b1[tid]; }
    __syncthreads();
    int i = blockIdx.x * blockDim.x + tid;
    if (i >= N_NODES) return;
    float di = dinv[i];
    float sv = s[i] + di * di * x[i];   // add self-loop contribution
    float h1[HID];
#pragma unroll
    for (int k = 0; k < HID; k++) h1[k] = fmaxf(sv * sW1[k] + sb1[k], 0.0f);
    float o[HID];
#pragma unroll
    for (int f = 0; f < HID; f++) o[f] = 0.0f;
#pragma unroll
    for (int k = 0; k < HID; k++) {
        float hk = h1[k];
#pragma unroll
        for (int f = 0; f < HID; f++) o[f] += hk * sW2[k * HID + f];
    }
    float4* dst = (float4*)(h2pre + (size_t)i * HID);
#pragma unroll
    for (int q = 0; q < HID / 4; q++)
        dst[q] = make_float4(o[4*q], o[4*q+1], o[4*q+2], o[4*q+3]);
}

// ---------------- Phase 5: heavy edge aggregation (conv2) --------------------
// thread t -> edge e = t/32, feature f = t%32
__global__ void agg_kernel(const int* __restrict__ row, const int* __restrict__ col,
                           const float* __restrict__ dinv,
                           const float* __restrict__ h2pre, float* __restrict__ agg2) {
    int t = blockIdx.x * blockDim.x + threadIdx.x;
    int e = t >> 5;
    int f = t & 31;
    if (e >= N_EDGES) return;
    int j = row[e], i = col[e];
    float norm = dinv[j] * dinv[i];
    float v = h2pre[(size_t)j * HID + f] * norm;
    atomicAdd(&agg2[(size_t)i * HID + f], v);
}

// ---------------- Phase 6: +self-loop, +b2, relu, segment_max pool -----------
__global__ void pool_kernel(const float* __restrict__ agg2, const float* __restrict__ h2pre,
                            const float* __restrict__ dinv, const float* __restrict__ b2,
                            const int* __restrict__ batch, unsigned int* __restrict__ g) {
    int t = blockIdx.x * blockDim.x + threadIdx.x;
    if (t >= N_NODES * HID) return;
    int i = t >> 5, f = t & 31;
    float di = dinv[i];
    float v = agg2[t] + di * di * h2pre[t] + b2[f];
    v = fmaxf(v, 0.0f);
    // non-negative floats: uint compare == float compare; g zero-init == 0.0f
    atomicMax(&g[(size_t)batch[i] * HID + f], __float_as_uint(v));
}

// ---------------- Phase 7: linear head + softmax -----------------------------
__global__ void head_kernel(const float* __restrict__ g, const float* __restrict__ Wl,
                            const float* __restrict__ bl, float* __restrict__ out) {
    int gid = blockIdx.x * blockDim.x + threadIdx.x;
    if (gid >= N_GRAPHS) return;
    float l0 = bl[0], l1 = bl[1];
#pragma unroll
    for (int k = 0; k < HID; k++) {
        float gv = g[(size_t)gid * HID + k];
        l0 += gv * Wl[2 * k];
        l1 += gv * Wl[2 * k + 1];
    }
    float m = fmaxf(l0, l1);
    float e0 = expf(l0 - m), e1 = expf(l1 - m);
    float inv = 1.0f / (e0 + e1);
    out[2 * gid]     = e0 * inv;
    out[2 * gid + 1] = e1 * inv;
}

extern "C" void kernel_launch(void* const* d_in, const int* in_sizes, int n_in,
                              void* d_out, int out_size, void* d_ws, size_t ws_size,
                              hipStream_t stream) {
    const float* x     = (const float*)d_in[0];
    const int*   ei    = (const int*)d_in[1];
    const int*   row   = ei;             // edge_index[0] = source j
    const int*   col   = ei + N_EDGES;   // edge_index[1] = target i
    const int*   batch = (const int*)d_in[2];
    const float* W1    = (const float*)d_in[3];
    const float* b1    = (const float*)d_in[4];
    const float* W2    = (const float*)d_in[5];
    const float* b2    = (const float*)d_in[6];
    const float* Wl    = (const float*)d_in[7];
    const float* bl    = (const float*)d_in[8];
    float* out = (float*)d_out;

    float* ws    = (float*)d_ws;
    float* deg   = ws;                                        // N   (becomes dinv)
    float* s     = ws + N_NODES;                              // N
    float* agg2  = ws + 2 * N_NODES;                          // N*32
    float* g     = ws + 2 * N_NODES + (size_t)N_NODES * HID;  // 512*32
    float* h2pre = g + (size_t)N_GRAPHS * HID;                // N*32

    size_t zero_floats = 2 * (size_t)N_NODES + (size_t)N_NODES * HID + (size_t)N_GRAPHS * HID;
    hipMemsetAsync(ws, 0, zero_floats * sizeof(float), stream);

    const int B = 256;
    deg_kernel <<<(N_EDGES + B - 1) / B, B, 0, stream>>>(col, deg);
    dinv_kernel<<<(N_NODES + B - 1) / B, B, 0, stream>>>(deg);
    s_kernel   <<<(N_EDGES + B - 1) / B, B, 0, stream>>>(row, col, x, deg, s);
    h2pre_kernel<<<(N_NODES + B - 1) / B, B, 0, stream>>>(x, deg, s, W1, b1, W2, h2pre);

    long long aggThreads = (long long)N_EDGES * HID;           // 102.4M
    agg_kernel <<<(int)((aggThreads + B - 1) / B), B, 0, stream>>>(row, col, deg, h2pre, agg2);

    int poolThreads = N_NODES * HID;                           // 3.2M
    pool_kernel<<<(poolThreads + B - 1) / B, B, 0, stream>>>(agg2, h2pre, deg, b2, batch,
                                                             (unsigned int*)g);
    head_kernel<<<(N_GRAPHS + B - 1) / B, B, 0, stream>>>(g, Wl, bl, out);
}

// Round 2
// 588.424 us; speedup vs baseline: 1.3751x; 1.3751x over previous
//
#include <hip/hip_runtime.h>

constexpr int N_NODES  = 100000;
constexpr int N_EDGES  = 3200000;
constexpr int N_GRAPHS = 512;
constexpr int HID      = 32;
constexpr int B        = 256;
constexpr int NBLK     = (N_NODES + B - 1) / B;   // 391

// ---------- Phase 1: integer in-degree count (edges only; self-loop via +1) --
__global__ void deg_count_kernel(const int* __restrict__ col, int* __restrict__ deg) {
    int e = blockIdx.x * blockDim.x + threadIdx.x;
    if (e < N_EDGES) atomicAdd(&deg[col[e]], 1);
}

// ---------- Phase 2a: per-block sums of deg ----------------------------------
__global__ void scanA_kernel(const int* __restrict__ deg, int* __restrict__ bsum) {
    __shared__ int tmp[B];
    int t = threadIdx.x, i = blockIdx.x * B + t;
    tmp[t] = (i < N_NODES) ? deg[i] : 0;
    __syncthreads();
    for (int ofs = B / 2; ofs > 0; ofs >>= 1) {
        if (t < ofs) tmp[t] += tmp[t + ofs];
        __syncthreads();
    }
    if (t == 0) bsum[blockIdx.x] = tmp[0];
}

// ---------- Phase 2b: exclusive scan of the 391 block sums (one block) -------
__global__ void scanB_kernel(int* __restrict__ bsum) {
    __shared__ int tmp[512];
    int t = threadIdx.x;
    tmp[t] = (t < NBLK) ? bsum[t] : 0;
    __syncthreads();
    for (int ofs = 1; ofs < 512; ofs <<= 1) {
        int v = (t >= ofs) ? tmp[t - ofs] : 0;
        __syncthreads();
        tmp[t] += v;
        __syncthreads();
    }
    if (t < NBLK) bsum[t] = t ? tmp[t - 1] : 0;   // exclusive
}

// ---------- Phase 2c: per-node exclusive offsets + dinv ----------------------
__global__ void scanC_kernel(const int* __restrict__ deg, const int* __restrict__ bsum,
                             int* __restrict__ offsets, float* __restrict__ dinv) {
    __shared__ int tmp[B];
    int t = threadIdx.x, i = blockIdx.x * B + t;
    int d = (i < N_NODES) ? deg[i] : 0;
    tmp[t] = d;
    __syncthreads();
    for (int ofs = 1; ofs < B; ofs <<= 1) {
        int v = (t >= ofs) ? tmp[t - ofs] : 0;
        __syncthreads();
        tmp[t] += v;
        __syncthreads();
    }
    if (i < N_NODES) {
        offsets[i] = (tmp[t] - d) + bsum[blockIdx.x];   // exclusive prefix
        dinv[i] = rsqrtf((float)d + 1.0f);              // +1 self-loop
    }
}

// ---------- Phase 3: scatter sources into CSR --------------------------------
__global__ void scatter_kernel(const int* __restrict__ row, const int* __restrict__ col,
                               const int* __restrict__ offsets, int* __restrict__ cursor,
                               int* __restrict__ csr_src) {
    int e = blockIdx.x * blockDim.x + threadIdx.x;
    if (e < N_EDGES) {
        int i = col[e];
        int pos = offsets[i] + atomicAdd(&cursor[i], 1);
        csr_src[pos] = row[e];
    }
}

// ---------- Phase 4: conv1 scalar agg, CSR gather, 8 lanes/node --------------
__global__ void s_csr_kernel(const int* __restrict__ csr_src, const int* __restrict__ offsets,
                             const int* __restrict__ deg, const float* __restrict__ x,
                             const float* __restrict__ dinv, float* __restrict__ s_tot) {
    int t = blockIdx.x * blockDim.x + threadIdx.x;
    int node = t >> 3, lane = t & 7;
    if (node >= N_NODES) return;
    int beg = offsets[node], d = deg[node];
    float acc = 0.0f;
    for (int e = beg + lane; e < beg + d; e += 8) {
        int j = csr_src[e];
        acc += dinv[j] * x[j];
    }
    acc += __shfl_down(acc, 4, 8);
    acc += __shfl_down(acc, 2, 8);
    acc += __shfl_down(acc, 1, 8);
    if (lane == 0) {
        float di = dinv[node];
        s_tot[node] = di * acc + di * di * x[node];   // neighbors + self-loop
    }
}

// ---------- Phase 5: per-node MLP: h2pre = relu(s*W1+b1) @ W2 ----------------
__global__ void mlp_kernel(const float* __restrict__ s_tot,
                           const float* __restrict__ W1, const float* __restrict__ b1,
                           const float* __restrict__ W2, float* __restrict__ h2pre) {
    __shared__ float sW1[HID], sb1[HID], sW2[HID * HID];
    int tid = threadIdx.x;
    for (int t = tid; t < HID * HID; t += blockDim.x) sW2[t] = W2[t];
    if (tid < HID) { sW1[tid] = W1[tid]; sb1[tid] = b1[tid]; }
    __syncthreads();
    int i = blockIdx.x * blockDim.x + tid;
    if (i >= N_NODES) return;
    float sv = s_tot[i];
    float h1[HID];
#pragma unroll
    for (int k = 0; k < HID; k++) h1[k] = fmaxf(sv * sW1[k] + sb1[k], 0.0f);
    float o[HID];
#pragma unroll
    for (int f = 0; f < HID; f++) o[f] = 0.0f;
#pragma unroll
    for (int k = 0; k < HID; k++) {
        float hk = h1[k];
#pragma unroll
        for (int f = 0; f < HID; f++) o[f] += hk * sW2[k * HID + f];
    }
    float4* dst = (float4*)(h2pre + (size_t)i * HID);
#pragma unroll
    for (int q = 0; q < HID / 4; q++)
        dst[q] = make_float4(o[4*q], o[4*q+1], o[4*q+2], o[4*q+3]);
}

// ---------- Phase 6: conv2 CSR gather + self-loop + b2 + relu + max-pool -----
// 32 lanes per node, lane = feature; register accumulation, no scatter atomics.
__global__ void conv2_pool_kernel(const int* __restrict__ csr_src, const int* __restrict__ offsets,
                                  const int* __restrict__ deg, const float* __restrict__ dinv,
                                  const float* __restrict__ h2pre, const float* __restrict__ b2,
                                  const int* __restrict__ batch, unsigned int* __restrict__ g) {
    int t = blockIdx.x * blockDim.x + threadIdx.x;
    int node = t >> 5, f = t & 31;
    if (node >= N_NODES) return;
    int beg = offsets[node];
    int end = beg + deg[node];
    float acc = 0.0f;
    for (int e = beg; e < end; ++e) {
        int j = csr_src[e];                         // broadcast within half-wave
        acc += dinv[j] * h2pre[(size_t)j * HID + f]; // coalesced 128B across lanes
    }
    float di = dinv[node];
    float v = di * acc + di * di * h2pre[(size_t)node * HID + f] + b2[f];
    v = fmaxf(v, 0.0f);
    // post-relu values are >= 0: uint compare == float compare; zero-init == 0.0f
    atomicMax(&g[(size_t)batch[node] * HID + f], __float_as_uint(v));
}

// ---------- Phase 7: linear head + softmax -----------------------------------
__global__ void head_kernel(const float* __restrict__ g, const float* __restrict__ Wl,
                            const float* __restrict__ bl, float* __restrict__ out) {
    int gid = blockIdx.x * blockDim.x + threadIdx.x;
    if (gid >= N_GRAPHS) return;
    float l0 = bl[0], l1 = bl[1];
#pragma unroll
    for (int k = 0; k < HID; k++) {
        float gv = g[(size_t)gid * HID + k];
        l0 += gv * Wl[2 * k];
        l1 += gv * Wl[2 * k + 1];
    }
    float m = fmaxf(l0, l1);
    float e0 = expf(l0 - m), e1 = expf(l1 - m);
    float inv = 1.0f / (e0 + e1);
    out[2 * gid]     = e0 * inv;
    out[2 * gid + 1] = e1 * inv;
}

extern "C" void kernel_launch(void* const* d_in, const int* in_sizes, int n_in,
                              void* d_out, int out_size, void* d_ws, size_t ws_size,
                              hipStream_t stream) {
    const float* x     = (const float*)d_in[0];
    const int*   ei    = (const int*)d_in[1];
    const int*   row   = ei;             // source j
    const int*   col   = ei + N_EDGES;   // target i
    const int*   batch = (const int*)d_in[2];
    const float* W1    = (const float*)d_in[3];
    const float* b1    = (const float*)d_in[4];
    const float* W2    = (const float*)d_in[5];
    const float* b2    = (const float*)d_in[6];
    const float* Wl    = (const float*)d_in[7];
    const float* bl    = (const float*)d_in[8];
    float* out = (float*)d_out;

    // ---- workspace layout (4B words) ----
    // [deg N][cursor N][g 16384][offsets N][dinv N][bsum 512][s_tot N][csr E][h2pre N*32]
    int*   deg     = (int*)d_ws;
    int*   cursor  = deg + N_NODES;
    unsigned int* g = (unsigned int*)(cursor + N_NODES);
    int*   offsets = (int*)(g + (size_t)N_GRAPHS * HID);
    float* dinv    = (float*)(offsets + N_NODES);
    int*   bsum    = (int*)(dinv + N_NODES);
    float* s_tot   = (float*)(bsum + 512);
    int*   csr_src = (int*)(s_tot + N_NODES);
    float* h2pre   = (float*)(csr_src + N_EDGES);

    // zero deg + cursor + g in one shot (contiguous)
    hipMemsetAsync(d_ws, 0, (2 * (size_t)N_NODES + (size_t)N_GRAPHS * HID) * sizeof(int), stream);

    deg_count_kernel<<<(N_EDGES + B - 1) / B, B, 0, stream>>>(col, deg);
    scanA_kernel<<<NBLK, B, 0, stream>>>(deg, bsum);
    scanB_kernel<<<1, 512, 0, stream>>>(bsum);
    scanC_kernel<<<NBLK, B, 0, stream>>>(deg, bsum, offsets, dinv);
    scatter_kernel<<<(N_EDGES + B - 1) / B, B, 0, stream>>>(row, col, offsets, cursor, csr_src);

    int sThreads = N_NODES * 8;
    s_csr_kernel<<<(sThreads + B - 1) / B, B, 0, stream>>>(csr_src, offsets, deg, x, dinv, s_tot);
    mlp_kernel<<<(N_NODES + B - 1) / B, B, 0, stream>>>(s_tot, W1, b1, W2, h2pre);

    long long cThreads = (long long)N_NODES * HID;   // 3.2M
    conv2_pool_kernel<<<(int)((cThreads + B - 1) / B), B, 0, stream>>>(
        csr_src, offsets, deg, dinv, h2pre, b2, batch, g);

    head_kernel<<<(N_GRAPHS + B - 1) / B, B, 0, stream>>>((const float*)g, Wl, bl, out);
}

// Round 3
// 514.741 us; speedup vs baseline: 1.5719x; 1.1431x over previous
//
#include <hip/hip_runtime.h>

constexpr int N_NODES  = 100000;
constexpr int N_EDGES  = 3200000;
constexpr int N_GRAPHS = 512;
constexpr int HID      = 32;
constexpr int B        = 256;
constexpr int NBLK     = (N_NODES + B - 1) / B;   // 391

// ---------- Phase 1: integer in-degree count (edges only; self-loop via +1) --
__global__ void deg_count_kernel(const int* __restrict__ col, int* __restrict__ deg) {
    int e = blockIdx.x * blockDim.x + threadIdx.x;
    if (e < N_EDGES) atomicAdd(&deg[col[e]], 1);
}

// ---------- Phase 2a: per-block sums of deg ----------------------------------
__global__ void scanA_kernel(const int* __restrict__ deg, int* __restrict__ bsum) {
    __shared__ int tmp[B];
    int t = threadIdx.x, i = blockIdx.x * B + t;
    tmp[t] = (i < N_NODES) ? deg[i] : 0;
    __syncthreads();
    for (int ofs = B / 2; ofs > 0; ofs >>= 1) {
        if (t < ofs) tmp[t] += tmp[t + ofs];
        __syncthreads();
    }
    if (t == 0) bsum[blockIdx.x] = tmp[0];
}

// ---------- Phase 2b: exclusive scan of the 391 block sums (one block) -------
__global__ void scanB_kernel(int* __restrict__ bsum) {
    __shared__ int tmp[512];
    int t = threadIdx.x;
    tmp[t] = (t < NBLK) ? bsum[t] : 0;
    __syncthreads();
    for (int ofs = 1; ofs < 512; ofs <<= 1) {
        int v = (t >= ofs) ? tmp[t - ofs] : 0;
        __syncthreads();
        tmp[t] += v;
        __syncthreads();
    }
    if (t < NBLK) bsum[t] = t ? tmp[t - 1] : 0;   // exclusive
}

// ---------- Phase 2c: offsets + dinv + xd = dinv*x ---------------------------
__global__ void scanC_kernel(const int* __restrict__ deg, const int* __restrict__ bsum,
                             const float* __restrict__ x,
                             int* __restrict__ offsets, float* __restrict__ dinv,
                             float* __restrict__ xd) {
    __shared__ int tmp[B];
    int t = threadIdx.x, i = blockIdx.x * B + t;
    int d = (i < N_NODES) ? deg[i] : 0;
    tmp[t] = d;
    __syncthreads();
    for (int ofs = 1; ofs < B; ofs <<= 1) {
        int v = (t >= ofs) ? tmp[t - ofs] : 0;
        __syncthreads();
        tmp[t] += v;
        __syncthreads();
    }
    if (i < N_NODES) {
        offsets[i] = (tmp[t] - d) + bsum[blockIdx.x];   // exclusive prefix
        float di = rsqrtf((float)d + 1.0f);             // +1 self-loop
        dinv[i] = di;
        xd[i] = di * x[i];
    }
}

// ---------- Phase 3: scatter sources into CSR --------------------------------
__global__ void scatter_kernel(const int* __restrict__ row, const int* __restrict__ col,
                               const int* __restrict__ offsets, int* __restrict__ cursor,
                               int* __restrict__ csr_src) {
    int e = blockIdx.x * blockDim.x + threadIdx.x;
    if (e < N_EDGES) {
        int i = col[e];
        int pos = offsets[i] + atomicAdd(&cursor[i], 1);
        csr_src[pos] = row[e];
    }
}

// ---------- Phase 4: conv1 scalar agg via CSR, 8 lanes/node, xd gather -------
__global__ void s_csr_kernel(const int* __restrict__ csr_src, const int* __restrict__ offsets,
                             const int* __restrict__ deg, const float* __restrict__ xd,
                             const float* __restrict__ dinv, float* __restrict__ s_tot) {
    int t = blockIdx.x * blockDim.x + threadIdx.x;
    int node = t >> 3, lane = t & 7;
    if (node >= N_NODES) return;
    int beg = offsets[node];
    int end = beg + deg[node];
    float acc = 0.0f;
    int e = beg + lane;
    // 2-way unroll (stride 8 per lane -> stride 16 per step)
    for (; e + 8 < end; e += 16) {
        int j0 = csr_src[e];
        int j1 = csr_src[e + 8];
        acc += xd[j0];
        acc += xd[j1];
    }
    if (e < end) acc += xd[csr_src[e]];
    acc += __shfl_down(acc, 4, 8);
    acc += __shfl_down(acc, 2, 8);
    acc += __shfl_down(acc, 1, 8);
    if (lane == 0) {
        float di = dinv[node];
        s_tot[node] = di * (acc + di * xd[node]);   // neighbors + self-loop (di^2 x)
    }
}

// ---------- Phase 5: per-node MLP: h2s = dinv * (relu(s*W1+b1) @ W2) ---------
__global__ void mlp_kernel(const float* __restrict__ s_tot, const float* __restrict__ dinv,
                           const float* __restrict__ W1, const float* __restrict__ b1,
                           const float* __restrict__ W2, float* __restrict__ h2s) {
    __shared__ float sW1[HID], sb1[HID], sW2[HID * HID];
    int tid = threadIdx.x;
    for (int t = tid; t < HID * HID; t += blockDim.x) sW2[t] = W2[t];
    if (tid < HID) { sW1[tid] = W1[tid]; sb1[tid] = b1[tid]; }
    __syncthreads();
    int i = blockIdx.x * blockDim.x + tid;
    if (i >= N_NODES) return;
    float sv = s_tot[i];
    float di = dinv[i];
    float h1[HID];
#pragma unroll
    for (int k = 0; k < HID; k++) h1[k] = fmaxf(sv * sW1[k] + sb1[k], 0.0f);
    float o[HID];
#pragma unroll
    for (int f = 0; f < HID; f++) o[f] = 0.0f;
#pragma unroll
    for (int k = 0; k < HID; k++) {
        float hk = h1[k];
#pragma unroll
        for (int f = 0; f < HID; f++) o[f] += hk * sW2[k * HID + f];
    }
    float4* dst = (float4*)(h2s + (size_t)i * HID);
#pragma unroll
    for (int q = 0; q < HID / 4; q++)
        dst[q] = make_float4(di * o[4*q], di * o[4*q+1], di * o[4*q+2], di * o[4*q+3]);
}

// ---------- Phase 6: conv2 gather (8-way ILP) + self-loop + b2 + relu + pool -
// 32 lanes per node, lane = feature. agg_i = dinv_i * (sum_j h2s[j] + h2s[i]).
__global__ void conv2_pool_kernel(const int* __restrict__ csr_src, const int* __restrict__ offsets,
                                  const int* __restrict__ deg, const float* __restrict__ dinv,
                                  const float* __restrict__ h2s, const float* __restrict__ b2,
                                  const int* __restrict__ batch, unsigned int* __restrict__ g) {
    int t = blockIdx.x * blockDim.x + threadIdx.x;
    int node = t >> 5, f = t & 31;
    if (node >= N_NODES) return;
    int beg = offsets[node];
    int end = beg + deg[node];
    float acc = 0.0f;
    int e = beg;
    // 8-way unroll: 8 independent index loads + 8 independent gathers in flight
    for (; e + 8 <= end; e += 8) {
        int j0 = csr_src[e + 0], j1 = csr_src[e + 1], j2 = csr_src[e + 2], j3 = csr_src[e + 3];
        int j4 = csr_src[e + 4], j5 = csr_src[e + 5], j6 = csr_src[e + 6], j7 = csr_src[e + 7];
        float v0 = h2s[(size_t)j0 * HID + f];
        float v1 = h2s[(size_t)j1 * HID + f];
        float v2 = h2s[(size_t)j2 * HID + f];
        float v3 = h2s[(size_t)j3 * HID + f];
        float v4 = h2s[(size_t)j4 * HID + f];
        float v5 = h2s[(size_t)j5 * HID + f];
        float v6 = h2s[(size_t)j6 * HID + f];
        float v7 = h2s[(size_t)j7 * HID + f];
        acc += ((v0 + v1) + (v2 + v3)) + ((v4 + v5) + (v6 + v7));
    }
    for (; e < end; ++e)
        acc += h2s[(size_t)csr_src[e] * HID + f];
    float di = dinv[node];
    float v = di * (acc + h2s[(size_t)node * HID + f]) + b2[f];
    v = fmaxf(v, 0.0f);
    // post-relu values >= 0: uint compare == float compare; zero-init == 0.0f
    atomicMax(&g[(size_t)batch[node] * HID + f], __float_as_uint(v));
}

// ---------- Phase 7: linear head + softmax -----------------------------------
__global__ void head_kernel(const float* __restrict__ g, const float* __restrict__ Wl,
                            const float* __restrict__ bl, float* __restrict__ out) {
    int gid = blockIdx.x * blockDim.x + threadIdx.x;
    if (gid >= N_GRAPHS) return;
    float l0 = bl[0], l1 = bl[1];
#pragma unroll
    for (int k = 0; k < HID; k++) {
        float gv = g[(size_t)gid * HID + k];
        l0 += gv * Wl[2 * k];
        l1 += gv * Wl[2 * k + 1];
    }
    float m = fmaxf(l0, l1);
    float e0 = expf(l0 - m), e1 = expf(l1 - m);
    float inv = 1.0f / (e0 + e1);
    out[2 * gid]     = e0 * inv;
    out[2 * gid + 1] = e1 * inv;
}

extern "C" void kernel_launch(void* const* d_in, const int* in_sizes, int n_in,
                              void* d_out, int out_size, void* d_ws, size_t ws_size,
                              hipStream_t stream) {
    const float* x     = (const float*)d_in[0];
    const int*   ei    = (const int*)d_in[1];
    const int*   row   = ei;             // source j
    const int*   col   = ei + N_EDGES;   // target i
    const int*   batch = (const int*)d_in[2];
    const float* W1    = (const float*)d_in[3];
    const float* b1    = (const float*)d_in[4];
    const float* W2    = (const float*)d_in[5];
    const float* b2    = (const float*)d_in[6];
    const float* Wl    = (const float*)d_in[7];
    const float* bl    = (const float*)d_in[8];
    float* out = (float*)d_out;

    // ---- workspace layout (4B words) ----
    // [deg N][cursor N][g 16384][offsets N][dinv N][xd N][bsum 512][s_tot N][csr E][h2s N*32]
    int*   deg     = (int*)d_ws;
    int*   cursor  = deg + N_NODES;
    unsigned int* g = (unsigned int*)(cursor + N_NODES);
    int*   offsets = (int*)(g + (size_t)N_GRAPHS * HID);
    float* dinv    = (float*)(offsets + N_NODES);
    float* xd      = dinv + N_NODES;
    int*   bsum    = (int*)(xd + N_NODES);
    float* s_tot   = (float*)(bsum + 512);
    int*   csr_src = (int*)(s_tot + N_NODES);
    float* h2s     = (float*)(csr_src + N_EDGES);

    // zero deg + cursor + g in one shot (contiguous)
    hipMemsetAsync(d_ws, 0, (2 * (size_t)N_NODES + (size_t)N_GRAPHS * HID) * sizeof(int), stream);

    deg_count_kernel<<<(N_EDGES + B - 1) / B, B, 0, stream>>>(col, deg);
    scanA_kernel<<<NBLK, B, 0, stream>>>(deg, bsum);
    scanB_kernel<<<1, 512, 0, stream>>>(bsum);
    scanC_kernel<<<NBLK, B, 0, stream>>>(deg, bsum, x, offsets, dinv, xd);
    scatter_kernel<<<(N_EDGES + B - 1) / B, B, 0, stream>>>(row, col, offsets, cursor, csr_src);

    int sThreads = N_NODES * 8;
    s_csr_kernel<<<(sThreads + B - 1) / B, B, 0, stream>>>(csr_src, offsets, deg, xd, dinv, s_tot);
    mlp_kernel<<<(N_NODES + B - 1) / B, B, 0, stream>>>(s_tot, dinv, W1, b1, W2, h2s);

    long long cThreads = (long long)N_NODES * HID;   // 3.2M
    conv2_pool_kernel<<<(int)((cThreads + B - 1) / B), B, 0, stream>>>(
        csr_src, offsets, deg, dinv, h2s, b2, batch, g);

    head_kernel<<<(N_GRAPHS + B - 1) / B, B, 0, stream>>>((const float*)g, Wl, bl, out);
}